// Round 3
// baseline (132.966 us; speedup 1.0000x reference)
//
#include <hip/hip_runtime.h>

#define D_MODEL 2048
#define NUM_TILES 64
#define D_SLICE 32
#define TILES_PER_CLUSTER 8
#define NUM_CLUSTERS 8
#define GRID_PTS 16
#define LN_EPS 1e-5f
#define NBUCKET 64

// order-preserving float<->uint map for atomic min/max
__device__ __forceinline__ unsigned int encF(float f) {
    unsigned int u = __float_as_uint(f);
    return (u & 0x80000000u) ? ~u : (u | 0x80000000u);
}
__device__ __forceinline__ float decF(unsigned int u) {
    unsigned int b = (u & 0x80000000u) ? (u ^ 0x80000000u) : ~u;
    return __uint_as_float(b);
}

// Kernel A: slope_sign per dim + init bucketed tile min/max (ws is poisoned).
__global__ void kan_setup(const float* __restrict__ slopes,
                          float* __restrict__ sgn,
                          unsigned int* __restrict__ tminb,
                          unsigned int* __restrict__ tmaxb) {
    int d = blockIdx.x * blockDim.x + threadIdx.x;  // 0..4095
    if (d < NUM_TILES * NBUCKET) { tminb[d] = 0xFFFFFFFFu; tmaxb[d] = 0u; }
    if (d < D_MODEL) {
        const float* p = slopes + (size_t)d * GRID_PTS;
        float s = 0.f;
#pragma unroll
        for (int k = 0; k < GRID_PTS; ++k) s += p[k];
        float m = s * (1.0f / GRID_PTS);
        sgn[d] = (m > 0.f) ? 1.f : ((m < 0.f) ? -1.f : 0.f);
    }
}

// 8-way constant-index select (avoids runtime-indexed register arrays -> scratch)
#define SEL8(dst, idx, A)                                              \
    dst = (idx == 0) ? A[0] : (idx == 1) ? A[1] : (idx == 2) ? A[2] :  \
          (idx == 3) ? A[3] : (idx == 4) ? A[4] : (idx == 5) ? A[5] :  \
          (idx == 6) ? A[6] : A[7];

// Kernel B: ONE WAVE PER TOKEN. No LDS, no barriers. Lane l owns dims
// {256*c + 4*l .. +3} for c=0..7 (unit-stride float4). Tile 8c+k lives in
// chunk c, lane-group k (lanes 8k..8k+7); cluster index == chunk index.
__launch_bounds__(256)
__global__ void kan_main(const float* __restrict__ x,
                         const float* __restrict__ gamma,
                         const float* __restrict__ beta,
                         const float* __restrict__ sgn,
                         float* __restrict__ out,
                         float* __restrict__ xn_slice,
                         int* __restrict__ tidx_out,
                         unsigned int* __restrict__ tminb,
                         unsigned int* __restrict__ tmaxb) {
    const int wid = threadIdx.x >> 6;
    const int l   = threadIdx.x & 63;
    const int n   = blockIdx.x * 4 + wid;
    const size_t rowb = (size_t)n * D_MODEL;

    const float* xr = x + rowb + 4 * l;
    float4 xv[8];
#pragma unroll
    for (int c = 0; c < 8; ++c) xv[c] = *(const float4*)(xr + 256 * c);

    // ---- mean (wave butterfly) ----
    float s = 0.f;
#pragma unroll
    for (int c = 0; c < 8; ++c) s += xv[c].x + xv[c].y + xv[c].z + xv[c].w;
#pragma unroll
    for (int off = 32; off > 0; off >>= 1) s += __shfl_xor(s, off);
    const float mu = s * (1.0f / D_MODEL);

    // ---- variance (wave butterfly) ----
    float v = 0.f;
#pragma unroll
    for (int c = 0; c < 8; ++c) {
        float dx = xv[c].x - mu, dy = xv[c].y - mu, dz = xv[c].z - mu, dw = xv[c].w - mu;
        v += dx * dx + dy * dy + dz * dz + dw * dw;
    }
#pragma unroll
    for (int off = 32; off > 0; off >>= 1) v += __shfl_xor(v, off);
    const float rs = rsqrtf(v * (1.0f / D_MODEL) + LN_EPS);

    // ---- out = x copy (overlaps with the rest) ----
    float* orow = out + rowb + 4 * l;
#pragma unroll
    for (int c = 0; c < 8; ++c) *(float4*)(orow + 256 * c) = xv[c];

    // ---- per-(chunk, lane) sign score; tile reduce within 8-lane groups ----
    const float* gr = gamma + 4 * l;
    const float* br = beta + 4 * l;
    const float* sr = sgn + 4 * l;
    int ts[8];
#pragma unroll
    for (int c = 0; c < 8; ++c) {
        float4 g  = *(const float4*)(gr + 256 * c);
        float4 bb = *(const float4*)(br + 256 * c);
        float4 sg = *(const float4*)(sr + 256 * c);
        float n0 = (xv[c].x - mu) * rs * g.x + bb.x;
        float n1 = (xv[c].y - mu) * rs * g.y + bb.y;
        float n2 = (xv[c].z - mu) * rs * g.z + bb.z;
        float n3 = (xv[c].w - mu) * rs * g.w + bb.w;
        int sc = 0;
        sc += ((n0 > 0.f) - (n0 < 0.f)) * (int)sg.x;
        sc += ((n1 > 0.f) - (n1 < 0.f)) * (int)sg.y;
        sc += ((n2 > 0.f) - (n2 < 0.f)) * (int)sg.z;
        sc += ((n3 > 0.f) - (n3 < 0.f)) * (int)sg.w;
        sc += __shfl_xor(sc, 1);
        sc += __shfl_xor(sc, 2);
        sc += __shfl_xor(sc, 4);
        ts[c] = sc;  // = tile_score[8c + (l>>3)], replicated in its 8-lane group
    }

    // ---- cluster sums: add across the 8 lane-groups ----
    int cs[8];
#pragma unroll
    for (int c = 0; c < 8; ++c) {
        int t = ts[c];
        t += __shfl_xor(t, 8);
        t += __shfl_xor(t, 16);
        t += __shfl_xor(t, 32);
        cs[c] = t;  // cluster_score[c], uniform across wave
    }

    // ---- cluster argmax (first-wins), lane-uniform ----
    int bc = 0, bv = cs[0];
#pragma unroll
    for (int c = 1; c < 8; ++c)
        if (cs[c] > bv) { bv = cs[c]; bc = c; }

    // ---- tile argmax within cluster bc: max over lane-groups, ties->smaller k
    int tsv;
    SEL8(tsv, bc, ts);
    const int k = l >> 3;
    int key = ((tsv + 64) << 3) | (7 - k);
    key = max(key, __shfl_xor(key, 8));
    key = max(key, __shfl_xor(key, 16));
    key = max(key, __shfl_xor(key, 32));
    const int kwin = 7 - (key & 7);
    const int tile = bc * 8 + kwin;  // uniform across wave

    // ---- recompute xn for chunk bc (chosen chunk == chosen cluster) ----
    float4 xs;
    SEL8(xs, bc, xv);
    float4 g  = *(const float4*)(gamma + 256 * bc + 4 * l);
    float4 bb = *(const float4*)(beta  + 256 * bc + 4 * l);
    float4 xn4;
    xn4.x = (xs.x - mu) * rs * g.x + bb.x;
    xn4.y = (xs.y - mu) * rs * g.y + bb.y;
    xn4.z = (xs.z - mu) * rs * g.z + bb.z;
    xn4.w = (xs.w - mu) * rs * g.w + bb.w;

    // ---- stash chosen tile's xn slice (group kwin only: 8 lanes, 128B) ----
    if (k == kwin)
        *(float4*)(xn_slice + (size_t)n * D_SLICE + 4 * (l & 7)) = xn4;

    // ---- tile min/max within the 8-lane group; atomics from one lane ----
    float mn = fminf(fminf(xn4.x, xn4.y), fminf(xn4.z, xn4.w));
    float mx = fmaxf(fmaxf(xn4.x, xn4.y), fmaxf(xn4.z, xn4.w));
    mn = fminf(mn, __shfl_xor(mn, 1));
    mn = fminf(mn, __shfl_xor(mn, 2));
    mn = fminf(mn, __shfl_xor(mn, 4));
    mx = fmaxf(mx, __shfl_xor(mx, 1));
    mx = fmaxf(mx, __shfl_xor(mx, 2));
    mx = fmaxf(mx, __shfl_xor(mx, 4));
    if (l == kwin * 8) {
        int bkt = n & (NBUCKET - 1);
        atomicMin(&tminb[tile * NBUCKET + bkt], encF(mn));
        atomicMax(&tmaxb[tile * NBUCKET + bkt], encF(mx));
    }
    if (l == 0) tidx_out[n] = tile;
}

// Kernel B2: reduce 64 buckets -> final per-tile min/max. One block, 64 thr.
__global__ void kan_reduce(const unsigned int* __restrict__ tminb,
                           const unsigned int* __restrict__ tmaxb,
                           unsigned int* __restrict__ tmin,
                           unsigned int* __restrict__ tmax) {
    int t = threadIdx.x;  // 0..63
    unsigned int mn = 0xFFFFFFFFu, mx = 0u;
#pragma unroll 4
    for (int b = 0; b < NBUCKET; ++b) {
        mn = min(mn, tminb[t * NBUCKET + b]);
        mx = max(mx, tmaxb[t * NBUCKET + b]);
    }
    tmin[t] = mn;
    tmax[t] = mx;
}

// Kernel C: one thread per (token, j). Spline delta, out += delta.
__global__ void kan_apply(const float* __restrict__ xn_slice,
                          const int* __restrict__ tidx,
                          const float* __restrict__ bases,
                          const float* __restrict__ slopes,
                          const float* __restrict__ oscale,
                          const unsigned int* __restrict__ tmin,
                          const unsigned int* __restrict__ tmax,
                          float* __restrict__ out, int N) {
    int g = blockIdx.x * blockDim.x + threadIdx.x;
    if (g >= N * D_SLICE) return;
    int n = g >> 5;
    int j = g & 31;
    int t = tidx[n];
    float xnv = xn_slice[g];
    float mn = decF(tmin[t]);
    float mx = decF(tmax[t]);
    float u = (xnv - mn) / (mx - mn + 1e-8f);
    u = fminf(fmaxf(u, 0.0f), 1.0f - 1e-6f);
    int gi = (int)(u * (float)GRID_PTS);
    gi = min(max(gi, 0), GRID_PTS - 1);
    int off = (t * D_SLICE + j) * GRID_PTS + gi;
    float bb = bases[off];
    float ss = slopes[off];
    float xl = (u - (float)gi * (1.0f / GRID_PTS)) * (float)GRID_PTS;
    float delta = (bb + ss * xl) * oscale[t];
    size_t oi = (size_t)n * D_MODEL + t * D_SLICE + j;
    out[oi] = out[oi] + delta;
}

extern "C" void kernel_launch(void* const* d_in, const int* in_sizes, int n_in,
                              void* d_out, int out_size, void* d_ws, size_t ws_size,
                              hipStream_t stream) {
    const float* x      = (const float*)d_in[0];
    const float* gamma  = (const float*)d_in[1];
    const float* beta   = (const float*)d_in[2];
    const float* bases  = (const float*)d_in[3];
    const float* slopes = (const float*)d_in[4];
    const float* oscale = (const float*)d_in[5];
    float* out = (float*)d_out;
    const int N = in_sizes[0] / D_MODEL;  // 16384

    // workspace layout
    char* w = (char*)d_ws;
    unsigned int* tminb = (unsigned int*)w; w += NUM_TILES * NBUCKET * 4;
    unsigned int* tmaxb = (unsigned int*)w; w += NUM_TILES * NBUCKET * 4;
    unsigned int* tmin  = (unsigned int*)w; w += 256;
    unsigned int* tmax  = (unsigned int*)w; w += 256;
    float* sgn = (float*)w;  w += D_MODEL * sizeof(float);
    int* tidx = (int*)w;     w += (size_t)N * sizeof(int);
    float* xns = (float*)w;  w += (size_t)N * D_SLICE * sizeof(float);

    kan_setup<<<(NUM_TILES * NBUCKET + 255) / 256, 256, 0, stream>>>(slopes, sgn, tminb, tmaxb);
    kan_main<<<N / 4, 256, 0, stream>>>(x, gamma, beta, sgn, out, xns, tidx, tminb, tmaxb);
    kan_reduce<<<1, 64, 0, stream>>>(tminb, tmaxb, tmin, tmax);
    kan_apply<<<(N * D_SLICE + 255) / 256, 256, 0, stream>>>(xns, tidx, bases, slopes,
                                                             oscale, tmin, tmax, out, N);
}

// Round 5
// 63.150 us; speedup vs baseline: 2.1055x; 2.1055x over previous
//
#include <hip/hip_runtime.h>

#define D_MODEL 2048
#define NUM_TILES 64
#define D_SLICE 32
#define TILES_PER_CLUSTER 8
#define NUM_CLUSTERS 8
#define GRID_PTS 16
#define LN_EPS 1e-5f
#define NBUCKET 64

// native 4-float vector (ext_vector_type works with __builtin_nontemporal_*)
typedef float f32x4 __attribute__((ext_vector_type(4)));

// order-preserving float<->uint map for atomic min/max
__device__ __forceinline__ unsigned int encF(float f) {
    unsigned int u = __float_as_uint(f);
    return (u & 0x80000000u) ? ~u : (u | 0x80000000u);
}
__device__ __forceinline__ float decF(unsigned int u) {
    unsigned int b = (u & 0x80000000u) ? (u ^ 0x80000000u) : ~u;
    return __uint_as_float(b);
}

// Kernel A: slope_sign per dim + init bucketed tile min/max (ws is poisoned).
__global__ void kan_setup(const float* __restrict__ slopes,
                          float* __restrict__ sgn,
                          unsigned int* __restrict__ tminb,
                          unsigned int* __restrict__ tmaxb) {
    int d = blockIdx.x * blockDim.x + threadIdx.x;  // 0..4095
    if (d < NUM_TILES * NBUCKET) { tminb[d] = 0xFFFFFFFFu; tmaxb[d] = 0u; }
    if (d < D_MODEL) {
        const float* p = slopes + (size_t)d * GRID_PTS;
        float s = 0.f;
#pragma unroll
        for (int k = 0; k < GRID_PTS; ++k) s += p[k];
        float m = s * (1.0f / GRID_PTS);
        sgn[d] = (m > 0.f) ? 1.f : ((m < 0.f) ? -1.f : 0.f);
    }
}

// Kernel B: one block per token (round-2 structure, no spill). Fused one-pass
// mean/var (E[x^2]-mu^2), early nontemporal out=x copy, hoisted weight loads,
// parallel argmax, bucketed low-contention atomics.
__launch_bounds__(256)
__global__ void kan_main(const float* __restrict__ x,
                         const float* __restrict__ gamma,
                         const float* __restrict__ beta,
                         const float* __restrict__ sgn,
                         float* __restrict__ out,
                         float* __restrict__ xn_slice,
                         int* __restrict__ tidx_out,
                         unsigned int* __restrict__ tminb,
                         unsigned int* __restrict__ tmaxb) {
    const int n = blockIdx.x;
    const int tid = threadIdx.x;
    const size_t base = (size_t)n * D_MODEL + (size_t)tid * 8;

    // load 8 contiguous dims (all within tile tid>>2)
    f32x4 a = *(const f32x4*)(x + base);
    f32x4 b = *(const f32x4*)(x + base + 4);

    // ---- out = x copy: issue immediately, nontemporal (don't pollute L3) ----
    __builtin_nontemporal_store(a, (f32x4*)(out + base));
    __builtin_nontemporal_store(b, (f32x4*)(out + base + 4));

    // ---- hoist weight loads (in flight during the reduction) ----
    f32x4 g0 = *(const f32x4*)(gamma + tid * 8);
    f32x4 g1 = *(const f32x4*)(gamma + tid * 8 + 4);
    f32x4 b0 = *(const f32x4*)(beta + tid * 8);
    f32x4 b1 = *(const f32x4*)(beta + tid * 8 + 4);
    f32x4 sg0 = *(const f32x4*)(sgn + tid * 8);
    f32x4 sg1 = *(const f32x4*)(sgn + tid * 8 + 4);

    float xv[8] = {a.x, a.y, a.z, a.w, b.x, b.y, b.z, b.w};

    __shared__ float2 red[4];
    __shared__ int ts[NUM_TILES];
    __shared__ int cs[NUM_CLUSTERS];
    __shared__ int chosen;

    // ---- fused sum + sumsq, single butterfly + single barrier ----
    float s = 0.f, q = 0.f;
#pragma unroll
    for (int k = 0; k < 8; ++k) { s += xv[k]; q += xv[k] * xv[k]; }
#pragma unroll
    for (int off = 32; off > 0; off >>= 1) {
        s += __shfl_xor(s, off);
        q += __shfl_xor(q, off);
    }
    if ((tid & 63) == 0) red[tid >> 6] = make_float2(s, q);
    __syncthreads();
    float S = red[0].x + red[1].x + red[2].x + red[3].x;
    float Q = red[0].y + red[1].y + red[2].y + red[3].y;
    const float mu = S * (1.0f / D_MODEL);
    float var = Q * (1.0f / D_MODEL) - mu * mu;
    var = fmaxf(var, 0.0f);
    const float rs = rsqrtf(var + LN_EPS);

    // ---- normalized values + integer sign score ----
    float gv[8] = {g0.x, g0.y, g0.z, g0.w, g1.x, g1.y, g1.z, g1.w};
    float bv[8] = {b0.x, b0.y, b0.z, b0.w, b1.x, b1.y, b1.z, b1.w};
    float sv[8] = {sg0.x, sg0.y, sg0.z, sg0.w, sg1.x, sg1.y, sg1.z, sg1.w};

    float xn[8];
    int sc = 0;
#pragma unroll
    for (int k = 0; k < 8; ++k) {
        xn[k] = (xv[k] - mu) * rs * gv[k] + bv[k];
        int s1 = (xn[k] > 0.f) ? 1 : ((xn[k] < 0.f) ? -1 : 0);
        sc += s1 * (int)sv[k];
    }
    sc += __shfl_xor(sc, 1);
    sc += __shfl_xor(sc, 2);
    if ((tid & 3) == 0) ts[tid >> 2] = sc;
    __syncthreads();

    // ---- argmax: 8 threads sum clusters in parallel, thread 0 compares ----
    if (tid < NUM_CLUSTERS) {
        int c = 0;
#pragma unroll
        for (int t = 0; t < TILES_PER_CLUSTER; ++t) c += ts[tid * TILES_PER_CLUSTER + t];
        cs[tid] = c;
    }
    __syncthreads();
    if (tid == 0) {
        int bc = 0, bv_ = -2147483647;
#pragma unroll
        for (int c = 0; c < NUM_CLUSTERS; ++c)
            if (cs[c] > bv_) { bv_ = cs[c]; bc = c; }
        int t0 = bc * TILES_PER_CLUSTER;
        int bt = t0, btv = ts[t0];
#pragma unroll
        for (int t = 1; t < TILES_PER_CLUSTER; ++t)
            if (ts[t0 + t] > btv) { btv = ts[t0 + t]; bt = t0 + t; }
        chosen = bt;
        tidx_out[n] = bt;
    }
    __syncthreads();
    const int tile = chosen;

    // ---- stash xn slice of chosen tile (4 threads, 128B contiguous) ----
    if ((tid >> 2) == tile) {
        float* qp = xn_slice + (size_t)n * D_SLICE + (tid & 3) * 8;
        *(f32x4*)(qp) = f32x4{xn[0], xn[1], xn[2], xn[3]};
        *(f32x4*)(qp + 4) = f32x4{xn[4], xn[5], xn[6], xn[7]};
    }

    // ---- chosen-tile min/max -> bucketed atomics (contention / 64) ----
    float mn8 = xn[0], mx8 = xn[0];
#pragma unroll
    for (int k = 1; k < 8; ++k) { mn8 = fminf(mn8, xn[k]); mx8 = fmaxf(mx8, xn[k]); }
    mn8 = fminf(mn8, __shfl_xor(mn8, 1));
    mn8 = fminf(mn8, __shfl_xor(mn8, 2));
    mx8 = fmaxf(mx8, __shfl_xor(mx8, 1));
    mx8 = fmaxf(mx8, __shfl_xor(mx8, 2));
    if (tid == tile * 4) {
        int bkt = blockIdx.x & (NBUCKET - 1);
        atomicMin(&tminb[tile * NBUCKET + bkt], encF(mn8));
        atomicMax(&tmaxb[tile * NBUCKET + bkt], encF(mx8));
    }
}

// Kernel B2: reduce 64 buckets -> final per-tile min/max. One block, 64 thr.
__global__ void kan_reduce(const unsigned int* __restrict__ tminb,
                           const unsigned int* __restrict__ tmaxb,
                           unsigned int* __restrict__ tmin,
                           unsigned int* __restrict__ tmax) {
    int t = threadIdx.x;  // 0..63
    unsigned int mn = 0xFFFFFFFFu, mx = 0u;
#pragma unroll 4
    for (int b = 0; b < NBUCKET; ++b) {
        mn = min(mn, tminb[t * NBUCKET + b]);
        mx = max(mx, tmaxb[t * NBUCKET + b]);
    }
    tmin[t] = mn;
    tmax[t] = mx;
}

// Kernel C: one thread per (token, quad). Spline delta, float4 RMW on out.
__global__ void kan_apply(const float* __restrict__ xn_slice,
                          const int* __restrict__ tidx,
                          const float* __restrict__ bases,
                          const float* __restrict__ slopes,
                          const float* __restrict__ oscale,
                          const unsigned int* __restrict__ tmin,
                          const unsigned int* __restrict__ tmax,
                          float* __restrict__ out, int N) {
    int g = blockIdx.x * blockDim.x + threadIdx.x;
    if (g >= N * 8) return;
    int n = g >> 3;
    int qd = g & 7;  // quad of 4 dims: j = 4*qd..4*qd+3
    int t = tidx[n];
    f32x4 xn4 = *(const f32x4*)(xn_slice + (size_t)n * D_SLICE + qd * 4);
    float mn = decF(tmin[t]);
    float mx = decF(tmax[t]);
    float inv = 1.0f / (mx - mn + 1e-8f);
    float osc = oscale[t];

    float dl[4];
    float xnv[4] = {xn4.x, xn4.y, xn4.z, xn4.w};
#pragma unroll
    for (int e = 0; e < 4; ++e) {
        float u = (xnv[e] - mn) * inv;
        u = fminf(fmaxf(u, 0.0f), 1.0f - 1e-6f);
        int gi = (int)(u * (float)GRID_PTS);
        gi = min(max(gi, 0), GRID_PTS - 1);
        int j = qd * 4 + e;
        int off = (t * D_SLICE + j) * GRID_PTS + gi;
        float xl = (u - (float)gi * (1.0f / GRID_PTS)) * (float)GRID_PTS;
        dl[e] = (bases[off] + slopes[off] * xl) * osc;
    }
    size_t oi = (size_t)n * D_MODEL + t * D_SLICE + qd * 4;
    f32x4 o = *(f32x4*)(out + oi);
    o.x += dl[0]; o.y += dl[1]; o.z += dl[2]; o.w += dl[3];
    *(f32x4*)(out + oi) = o;
}

extern "C" void kernel_launch(void* const* d_in, const int* in_sizes, int n_in,
                              void* d_out, int out_size, void* d_ws, size_t ws_size,
                              hipStream_t stream) {
    const float* x      = (const float*)d_in[0];
    const float* gamma  = (const float*)d_in[1];
    const float* beta   = (const float*)d_in[2];
    const float* bases  = (const float*)d_in[3];
    const float* slopes = (const float*)d_in[4];
    const float* oscale = (const float*)d_in[5];
    float* out = (float*)d_out;
    const int N = in_sizes[0] / D_MODEL;  // 16384

    // workspace layout
    char* w = (char*)d_ws;
    unsigned int* tminb = (unsigned int*)w; w += NUM_TILES * NBUCKET * 4;
    unsigned int* tmaxb = (unsigned int*)w; w += NUM_TILES * NBUCKET * 4;
    unsigned int* tmin  = (unsigned int*)w; w += 256;
    unsigned int* tmax  = (unsigned int*)w; w += 256;
    float* sgn = (float*)w;  w += D_MODEL * sizeof(float);
    int* tidx = (int*)w;     w += (size_t)N * sizeof(int);
    float* xns = (float*)w;  w += (size_t)N * D_SLICE * sizeof(float);

    kan_setup<<<(NUM_TILES * NBUCKET + 255) / 256, 256, 0, stream>>>(slopes, sgn, tminb, tmaxb);
    kan_main<<<N, 256, 0, stream>>>(x, gamma, beta, sgn, out, xns, tidx, tminb, tmaxb);
    kan_reduce<<<1, 64, 0, stream>>>(tminb, tmaxb, tmin, tmax);
    kan_apply<<<(N * 8 + 255) / 256, 256, 0, stream>>>(xns, tidx, bases, slopes,
                                                       oscale, tmin, tmax, out, N);
}